// Round 2
// baseline (234.327 us; speedup 1.0000x reference)
//
#include <hip/hip_runtime.h>
#include <hip/hip_bf16.h>

// Problem: B,W,H,L = 2,32,32,32 -> N=65536 voxels; D=512, E=64 heads, V=16.
// Float tensors are fp32 on device (NaN diagnosis round 1); output fp32.
// Strategy: exact counting-sort of voxels by head, then one MFMA wave per
// 16-voxel tile (fp32 loads -> RNE bf16 convert -> mfma_f32_16x16x32_bf16).
#define DDIM 512
#define VDIM 16
#define EHEADS 64
#define NVOX 65536
#define MAXT (NVOX / 16 + EHEADS)   // 4160 worst-case tiles (all remainders)

typedef __bf16  bf16x8  __attribute__((ext_vector_type(8)));
typedef float   floatx4 __attribute__((ext_vector_type(4)));

// ---- workspace layout (int offsets) ---------------------------------------
// [0,64)      counts        (memset to 0 by kernel_launch)
// [64,129)    offsets[65]   exclusive prefix of counts
// [132]       ntiles
// [136,200)   cursor[64]    (zeroed by plan kernel)
// [256, +MAXT)        tile_head
// [256+MAXT, +MAXT)   tile_rs      (absolute row start in list)
// [256+2*MAXT, +NVOX) list
#define WS_COUNTS  0
#define WS_OFFSETS 64
#define WS_NTILES  132
#define WS_CURSOR  136
#define WS_THEAD   256
#define WS_TRS     (WS_THEAD + MAXT)
#define WS_LIST    (WS_TRS + MAXT)
#define WS_NEED_INTS (WS_LIST + NVOX)

// ---------------------------------------------------------------------------
__global__ __launch_bounds__(256) void hist_kernel(
    const int* __restrict__ btg, const int* __restrict__ b2h,
    int* __restrict__ ws)
{
    __shared__ int lc[EHEADS];
    const int tid = threadIdx.x;
    if (tid < EHEADS) lc[tid] = 0;
    __syncthreads();
    const int n = blockIdx.x * 256 + tid;
    const int h = b2h[btg[n]];
    atomicAdd(&lc[h], 1);
    __syncthreads();
    if (tid < EHEADS && lc[tid] > 0) atomicAdd(&ws[WS_COUNTS + tid], lc[tid]);
}

// single block, 64 threads: prefix sums + flat tile plan
__global__ __launch_bounds__(64) void plan_kernel(int* __restrict__ ws)
{
    __shared__ int offs[EHEADS + 1];
    __shared__ int tbase[EHEADS];
    const int tid = threadIdx.x;
    ws[WS_CURSOR + tid] = 0;
    if (tid == 0) {
        int run = 0, trun = 0;
        for (int h = 0; h < EHEADS; ++h) {
            const int c = ws[WS_COUNTS + h];
            offs[h] = run;  ws[WS_OFFSETS + h] = run;  run += c;
            tbase[h] = trun; trun += (c + 15) >> 4;
        }
        offs[EHEADS] = run; ws[WS_OFFSETS + EHEADS] = run;
        ws[WS_NTILES] = trun;
    }
    __syncthreads();
    const int c  = ws[WS_COUNTS + tid];
    const int nt = (c + 15) >> 4;
    const int tb = tbase[tid], o0 = offs[tid];
    for (int i = 0; i < nt; ++i) {
        ws[WS_THEAD + tb + i] = tid;
        ws[WS_TRS   + tb + i] = o0 + 16 * i;
    }
}

__global__ __launch_bounds__(256) void scatter_kernel(
    const int* __restrict__ btg, const int* __restrict__ b2h,
    int* __restrict__ ws)
{
    __shared__ int lc[EHEADS];
    __shared__ int lb[EHEADS];
    const int tid = threadIdx.x;
    if (tid < EHEADS) lc[tid] = 0;
    __syncthreads();
    const int n = blockIdx.x * 256 + tid;
    const int h = b2h[btg[n]];
    const int my = atomicAdd(&lc[h], 1);
    __syncthreads();
    if (tid < EHEADS) {
        const int c = lc[tid];
        lb[tid] = (c > 0) ? atomicAdd(&ws[WS_CURSOR + tid], c) : 0;
    }
    __syncthreads();
    ws[WS_LIST + ws[WS_OFFSETS + h] + lb[h] + my] = n;
}

// ---------------------------------------------------------------------------
// One wave per tile of <=16 same-head voxels.
//   A[m][k] = x[idx[m]][k]   (m=lane&15, k=quad*8+j per K=32 step)
//   B[k][n] = W[e][n][k]     (n=lane&15; W (E,V,D) is already B^T)
//   D: col=lane&15, row=quad*4+reg
// ---------------------------------------------------------------------------
__global__ __launch_bounds__(256) void decode_kernel(
    const float* __restrict__ x,    // (NVOX, D) fp32
    const float* __restrict__ Wh,   // (E, V, D) fp32
    const float* __restrict__ bh,   // (E, V)    fp32
    const int* __restrict__ ws,
    float* __restrict__ out)        // (NVOX, V) fp32
{
    const int wv   = threadIdx.x >> 6;
    const int lane = threadIdx.x & 63;
    const int t    = blockIdx.x * 4 + wv;
    if (t >= ws[WS_NTILES]) return;

    const int e  = ws[WS_THEAD + t];
    const int rs = ws[WS_TRS + t];
    const int re = ws[WS_OFFSETS + e + 1];

    const int m    = lane & 15;
    const int quad = lane >> 4;

    int rm = rs + m;
    if (rm > re - 1) rm = re - 1;          // clamp tail (dupes not stored)
    const int idx_m = ws[WS_LIST + rm];

    const floatx4* __restrict__ xr =
        (const floatx4*)(x + (size_t)idx_m * DDIM + quad * 8);
    const floatx4* __restrict__ wr =
        (const floatx4*)(Wh + ((size_t)e * VDIM + m) * DDIM + quad * 8);

    floatx4 acc = {0.f, 0.f, 0.f, 0.f};
#pragma unroll
    for (int k0 = 0; k0 < DDIM / 32; ++k0) {
        const floatx4 a0 = xr[k0 * 8], a1 = xr[k0 * 8 + 1];
        const floatx4 b0 = wr[k0 * 8], b1 = wr[k0 * 8 + 1];
        bf16x8 af, bf;
#pragma unroll
        for (int j = 0; j < 4; ++j) {
            af[j] = (__bf16)a0[j]; af[4 + j] = (__bf16)a1[j];
            bf[j] = (__bf16)b0[j]; bf[4 + j] = (__bf16)b1[j];
        }
        acc = __builtin_amdgcn_mfma_f32_16x16x32_bf16(af, bf, acc, 0, 0, 0);
    }

    const float bv = bh[e * VDIM + m];
#pragma unroll
    for (int r = 0; r < 4; ++r) {
        const int o = rs + quad * 4 + r;
        if (o < re)
            out[(size_t)ws[WS_LIST + o] * VDIM + m] = acc[r] + bv;
    }
}

// ---------------------------------------------------------------------------
// Fallback if ws is too small: one wave per voxel, fp32 VALU dot products.
// ---------------------------------------------------------------------------
__global__ __launch_bounds__(256) void naive_kernel(
    const int* __restrict__ btg, const int* __restrict__ b2h,
    const float* __restrict__ x, const float* __restrict__ Wh,
    const float* __restrict__ bh, float* __restrict__ out)
{
    const int wv   = threadIdx.x >> 6;
    const int lane = threadIdx.x & 63;
    const int n    = blockIdx.x * 4 + wv;
    const int h    = b2h[btg[n]];
    const int v    = lane >> 2;
    const int q    = lane & 3;

    const floatx4* __restrict__ xp =
        (const floatx4*)(x + (size_t)n * DDIM + q * 128);
    const floatx4* __restrict__ wp =
        (const floatx4*)(Wh + ((size_t)h * VDIM + v) * DDIM + q * 128);

    float s = 0.f;
#pragma unroll
    for (int i = 0; i < 32; ++i) {
        const floatx4 a = xp[i], b = wp[i];
        s += a[0] * b[0] + a[1] * b[1] + a[2] * b[2] + a[3] * b[3];
    }
    s += __shfl_xor(s, 1);
    s += __shfl_xor(s, 2);
    if (q == 0) out[(size_t)n * VDIM + v] = s + bh[h * VDIM + v];
}

extern "C" void kernel_launch(void* const* d_in, const int* in_sizes, int n_in,
                              void* d_out, int out_size, void* d_ws, size_t ws_size,
                              hipStream_t stream)
{
    const int*   btg = (const int*)d_in[0];
    const float* x   = (const float*)d_in[1];
    const float* Wh  = (const float*)d_in[2];
    const float* bh  = (const float*)d_in[3];
    const int*   b2h = (const int*)d_in[4];
    float*       out = (float*)d_out;

    if (ws_size >= (size_t)WS_NEED_INTS * sizeof(int)) {
        int* ws = (int*)d_ws;
        hipMemsetAsync(ws, 0, EHEADS * sizeof(int), stream);  // counts only
        hist_kernel<<<NVOX / 256, 256, 0, stream>>>(btg, b2h, ws);
        plan_kernel<<<1, 64, 0, stream>>>(ws);
        scatter_kernel<<<NVOX / 256, 256, 0, stream>>>(btg, b2h, ws);
        decode_kernel<<<MAXT / 4, 256, 0, stream>>>(x, Wh, bh, ws, out);
    } else {
        naive_kernel<<<NVOX / 4, 256, 0, stream>>>(btg, b2h, x, Wh, bh, out);
    }
}

// Round 3
// 231.108 us; speedup vs baseline: 1.0139x; 1.0139x over previous
//
#include <hip/hip_runtime.h>
#include <hip/hip_bf16.h>

// Problem: B,W,H,L = 2,32,32,32 -> N=65536 voxels; D=512, E=64 heads, V=16.
// fp32 tensors on device; out fp32. Single fused kernel:
//   grid = 64 heads x 32 sub-ranges. Each block ballot-compacts the voxel
//   indices in its 2048-voxel slice that route to its head (LDS list), then
//   decodes them with mfma_f32_16x16x32_bf16 (fp32 -> RNE bf16 in-register).
// No workspace, no global atomics, one launch.
#define DDIM 512
#define VDIM 16
#define EHEADS 64
#define NVOX 65536
#define BLOCKS_PER_HEAD 32
#define RANGE (NVOX / BLOCKS_PER_HEAD)       // 2048 voxels per block slice
#define NBLOCKS (EHEADS * BLOCKS_PER_HEAD)   // 2048 blocks

typedef __bf16  bf16x8  __attribute__((ext_vector_type(8)));
typedef float   floatx4 __attribute__((ext_vector_type(4)));

__global__ __launch_bounds__(256) void fused_decode_kernel(
    const int*   __restrict__ btg,   // (NVOX,) block types
    const int*   __restrict__ b2h,   // (256,)  block -> head
    const float* __restrict__ x,     // (NVOX, D)
    const float* __restrict__ Wh,    // (E, V, D)  == B^T layout for MFMA
    const float* __restrict__ bh,    // (E, V)
    float*       __restrict__ out)   // (NVOX, V)
{
    __shared__ int lut[256];
    __shared__ int list[RANGE];
    __shared__ int cursor;

    const int tid  = threadIdx.x;
    const int lane = tid & 63;
    const int wv   = tid >> 6;                 // wave id in block (0..3)
    const int e    = blockIdx.x >> 5;          // head
    const int q    = blockIdx.x & 31;          // sub-range
    const int base = q * RANGE;

    lut[tid] = b2h[tid];                       // blockDim == 256 == NUM_BLOCKS
    if (tid == 0) cursor = 0;
    __syncthreads();

    // ---- Phase 1: ballot-compact matching voxel indices into LDS ----------
#pragma unroll
    for (int it = 0; it < RANGE / 256; ++it) {
        const int n = base + it * 256 + tid;
        const bool match = (lut[btg[n]] == e);
        const unsigned long long mask = __ballot(match);
        const int pre = __popcll(mask & ((1ull << lane) - 1ull));
        int wb = 0;
        if (lane == 0) wb = atomicAdd(&cursor, __popcll(mask));
        wb = __shfl(wb, 0);
        if (match) list[wb + pre] = n;
    }
    __syncthreads();
    const int cnt = cursor;                    // block-uniform
    if (cnt == 0) return;                      // no barriers after this point

    const int m    = lane & 15;
    const int quad = lane >> 4;

    // ---- Preload this head's full B operand into registers -----------------
    //   B[k][v] = W[e][v][k], v = m, k = k0*32 + quad*8 + j
    const floatx4* __restrict__ wr =
        (const floatx4*)(Wh + ((size_t)e * VDIM + m) * DDIM + quad * 8);
    bf16x8 bfr[DDIM / 32];
#pragma unroll
    for (int k0 = 0; k0 < DDIM / 32; ++k0) {
        const floatx4 b0 = wr[k0 * 8], b1 = wr[k0 * 8 + 1];
#pragma unroll
        for (int j = 0; j < 4; ++j) {
            bfr[k0][j] = (__bf16)b0[j]; bfr[k0][4 + j] = (__bf16)b1[j];
        }
    }
    const float bv = bh[e * VDIM + m];

    // ---- Phase 2: one wave per 16-voxel tile -------------------------------
    //   A[m'][k] = x[list[rs+m']][k];  D: col=lane&15, row=quad*4+reg
    for (int t = wv; t * 16 < cnt; t += 4) {
        const int rs = t * 16;
        int rm = rs + m;
        if (rm > cnt - 1) rm = cnt - 1;        // clamp tail (stores guarded)
        const int idx_m = list[rm];
        const floatx4* __restrict__ xr =
            (const floatx4*)(x + (size_t)idx_m * DDIM + quad * 8);

        floatx4 acc = {0.f, 0.f, 0.f, 0.f};
#pragma unroll
        for (int k0 = 0; k0 < DDIM / 32; ++k0) {
            const floatx4 a0 = xr[k0 * 8], a1 = xr[k0 * 8 + 1];
            bf16x8 af;
#pragma unroll
            for (int j = 0; j < 4; ++j) {
                af[j] = (__bf16)a0[j]; af[4 + j] = (__bf16)a1[j];
            }
            acc = __builtin_amdgcn_mfma_f32_16x16x32_bf16(af, bfr[k0], acc, 0, 0, 0);
        }

#pragma unroll
        for (int r = 0; r < 4; ++r) {
            const int o = rs + quad * 4 + r;
            if (o < cnt)
                out[(size_t)list[o] * VDIM + m] = acc[r] + bv;
        }
    }
}

extern "C" void kernel_launch(void* const* d_in, const int* in_sizes, int n_in,
                              void* d_out, int out_size, void* d_ws, size_t ws_size,
                              hipStream_t stream)
{
    const int*   btg = (const int*)d_in[0];
    const float* x   = (const float*)d_in[1];
    const float* Wh  = (const float*)d_in[2];
    const float* bh  = (const float*)d_in[3];
    const int*   b2h = (const int*)d_in[4];
    float*       out = (float*)d_out;
    (void)d_ws; (void)ws_size; (void)in_sizes; (void)n_in; (void)out_size;

    fused_decode_kernel<<<NBLOCKS, 256, 0, stream>>>(btg, b2h, x, Wh, bh, out);
}

// Round 4
// 225.868 us; speedup vs baseline: 1.0375x; 1.0232x over previous
//
#include <hip/hip_runtime.h>
#include <hip/hip_bf16.h>

// Problem: B,W,H,L = 2,32,32,32 -> N=65536 voxels; D=512, E=64 heads, V=16.
// fp32 tensors on device; out fp32. Single fused kernel, no workspace:
//   grid = 64 heads x 16 slices (1024 blocks, 4/CU). Each block:
//     1. stages W[head] into LDS as bf16 in MFMA-fragment order
//        (Wfrag[k0*64+lane] -> per-k0 ds_read_b128 with lanes reading
//        consecutive 16B: conflict-free, and no giant VGPR array to spill)
//     2. ballot-compacts its 4096-voxel slice's matching indices into LDS
//     3. one wave per 16-voxel tile: x gather (2 KB/row, full-line use) ->
//        RNE bf16 -> mfma_f32_16x16x32_bf16, B from LDS.
#define DDIM 512
#define VDIM 16
#define EHEADS 64
#define NVOX 65536
#define QPERH 16
#define SLICE (NVOX / QPERH)          // 4096 voxels per slice
#define NBLOCKS (EHEADS * QPERH)      // 1024 blocks
#define CAPL 2048                     // slice match cap (expect <=~250; see note)
#define KSTEPS (DDIM / 32)            // 16 MFMA K-steps

typedef __bf16  bf16x8  __attribute__((ext_vector_type(8)));
typedef float   floatx4 __attribute__((ext_vector_type(4)));

__global__ __launch_bounds__(256) void fused_decode_kernel(
    const int*   __restrict__ btg,   // (NVOX,)
    const int*   __restrict__ b2h,   // (256,)
    const float* __restrict__ x,     // (NVOX, D)
    const float* __restrict__ Wh,    // (E, V, D)
    const float* __restrict__ bh,    // (E, V)
    float*       __restrict__ out)   // (NVOX, V)
{
    __shared__ int    lut[256];
    __shared__ int    list[CAPL];                 // 8 KB
    __shared__ bf16x8 Wfrag[KSTEPS * 64];         // 16 KB, fragment order
    __shared__ int    cursor;

    const int tid  = threadIdx.x;
    const int lane = tid & 63;
    const int wv   = tid >> 6;                    // wave in block (0..3)
    const int e    = blockIdx.x >> 4;             // head
    const int q    = blockIdx.x & (QPERH - 1);    // slice
    const int m    = lane & 15;
    const int quad = lane >> 4;

    lut[tid] = b2h[tid];                          // blockDim == 256 types
    if (tid == 0) cursor = 0;
    __syncthreads();

    // ---- Stage W[e] -> LDS in fragment order (bf16), once per block -------
    // Wfrag[k0*64 + ln] = W[e][ln&15][k0*32 + (ln>>4)*8 + j], j=0..7
#pragma unroll
    for (int i = 0; i < 4; ++i) {
        const int f  = i * 256 + tid;             // fragment id 0..1023
        const int k0 = f >> 6;
        const int ln = f & 63;
        const float* src = Wh + ((size_t)e * VDIM + (ln & 15)) * DDIM
                              + k0 * 32 + (ln >> 4) * 8;
        const floatx4 b0 = *(const floatx4*)src;
        const floatx4 b1 = *(const floatx4*)(src + 4);
        bf16x8 bf;
#pragma unroll
        for (int j = 0; j < 4; ++j) {
            bf[j] = (__bf16)b0[j]; bf[4 + j] = (__bf16)b1[j];
        }
        Wfrag[f] = bf;                            // ds_write_b128, lane-seq
    }

    // ---- Ballot-compact matching voxel indices into LDS --------------------
    const int base = q * SLICE;
#pragma unroll 4
    for (int it = 0; it < SLICE / 256; ++it) {
        const int n = base + it * 256 + tid;      // coalesced btg read
        const bool match = (lut[btg[n]] == e);
        const unsigned long long mask = __ballot(match);
        int wb = 0;
        if (lane == 0) wb = atomicAdd(&cursor, __popcll(mask));
        wb = __shfl(wb, 0);
        if (match) {
            const int p = wb + __popcll(mask & ((1ull << lane) - 1ull));
            if (p < CAPL) list[p] = n;            // cap: needs K_h>128 to hit
        }
    }
    __syncthreads();

    int cnt = cursor;
    if (cnt > CAPL) cnt = CAPL;
    const int ntiles = (cnt + 15) >> 4;
    const float bv = bh[e * VDIM + m];

    // ---- Decode: one wave per tile, strided ---------------------------------
    for (int t = wv; t < ntiles; t += 4) {
        const int rs = t * 16;
        int rm = rs + m;
        if (rm >= cnt) rm = cnt - 1;              // clamp tail (stores guarded)
        const int idx_m = list[rm];               // LDS, quad-broadcast
        const float* __restrict__ xr = x + (size_t)idx_m * DDIM + quad * 8;

        floatx4 acc = {0.f, 0.f, 0.f, 0.f};
#pragma unroll
        for (int k0 = 0; k0 < KSTEPS; ++k0) {
            const floatx4 a0 = *(const floatx4*)(xr + k0 * 32);
            const floatx4 a1 = *(const floatx4*)(xr + k0 * 32 + 4);
            const bf16x8  bf = Wfrag[k0 * 64 + lane];   // ds_read_b128
            bf16x8 af;
#pragma unroll
            for (int j = 0; j < 4; ++j) {
                af[j] = (__bf16)a0[j]; af[4 + j] = (__bf16)a1[j];
            }
            acc = __builtin_amdgcn_mfma_f32_16x16x32_bf16(af, bf, acc, 0, 0, 0);
        }

        // D: col = m (output v), row = quad*4 + r (voxel within tile)
#pragma unroll
        for (int r = 0; r < 4; ++r) {
            const int o = rs + quad * 4 + r;
            if (o < cnt)
                out[(size_t)list[o] * VDIM + m] = acc[r] + bv;
        }
    }
}

extern "C" void kernel_launch(void* const* d_in, const int* in_sizes, int n_in,
                              void* d_out, int out_size, void* d_ws, size_t ws_size,
                              hipStream_t stream)
{
    const int*   btg = (const int*)d_in[0];
    const float* x   = (const float*)d_in[1];
    const float* Wh  = (const float*)d_in[2];
    const float* bh  = (const float*)d_in[3];
    const int*   b2h = (const int*)d_in[4];
    float*       out = (float*)d_out;
    (void)d_ws; (void)ws_size; (void)in_sizes; (void)n_in; (void)out_size;

    fused_decode_kernel<<<NBLOCKS, 256, 0, stream>>>(btg, b2h, x, Wh, bh, out);
}